// Round 4
// baseline (650.140 us; speedup 1.0000x reference)
//
#include <hip/hip_runtime.h>
#include <math.h>

// Sinkhorn W2, 16 pairs of 128x128, UNNORMALIZED linear-domain iteration
// (scale self-stabilizes; f32-safe), split 8 row-bands per pair over
// 128 blocks. Per halfstep: band-local row conv -> publish 16 D-rows to
// global ring(2) -> neighbor epoch-flag sync -> col conv over own+halo
// rows -> S' = max(a,1e-20)/T  (all band-local). Loss partials reduced
// deterministically by a finishing kernel.
#define RW 16
#define NHALF 20
#define NTH 256
#define NBLK 128
#define STS 161          // S row stride: 16 guard + 128 data + 17 guard
#define SDAT 16
#define DT0 2576         // D^T base (col-major rows of 48+1 pad)
#define STD 49
#define REDO 8848
#define LDSD 8856

struct GTab { float g[RW + 1]; };

__global__ __launch_bounds__(256, 1)
void sw2_init(unsigned int* __restrict__ ws) {
    unsigned int i = blockIdx.x * 256 + threadIdx.x;
    if (i < 2048) ws[i] = 0u;          // zero epoch flags
}

__global__ __launch_bounds__(NTH, 1)
void sw2_main(const float* __restrict__ a0, const float* __restrict__ a1,
              float* __restrict__ ws, GTab gt)
{
    __shared__ float lds[LDSD];
    const int t = threadIdx.x;
    const int blk = blockIdx.x;
    const int band = blk & 7, pair = blk >> 3;
    unsigned int* flags = (unsigned int*)ws;         // [0,2048) dwords, stride 16
    float* part = ws + 2048;                         // [2048,2176)
    float* bufs = ws + 4096;                         // 128 blk x 2 slots x 2048
    float* myb0 = bufs + (blk * 2) * 2048;
    float* myb1 = myb0 + 2048;

    const float* __restrict__ A0 = a0 + (pair >> 2) * 16384 + band * 2048;
    const float* __restrict__ A1 = a1 + (pair & 3) * 16384 + band * 2048;

    const int r1 = t & 15, ob = (t >> 4) << 3;   // phase-1 mapping (row, 8 cols)
    const int c2 = t & 127, rob = t >> 7;        // phase-2 mapping (col, 8 rows)

    for (int i = t; i < LDSD; i += NTH) lds[i] = 0.0f;
    __syncthreads();
    #pragma unroll
    for (int m = 0; m < 8; ++m) {                // S = exp(phi1=0) = 1
        int idx = t + NTH * m;
        lds[(idx >> 7) * STS + SDAT + (idx & 127)] = 1.0f;
    }

    float Ap0[8], Ap1[8];
    float SA1C = 0.f, D0 = 0.f, D1 = 0.f;
    #pragma unroll
    for (int j = 0; j < 8; ++j) {
        Ap0[j] = A0[(rob * 8 + j) * 128 + c2];
        Ap1[j] = A1[(rob * 8 + j) * 128 + c2];
        SA1C += fmaxf(Ap1[j], 1e-20f);           // sum p == sum max(a1,floor)
    }
    __syncthreads();

    #pragma unroll 1
    for (int k = 0; k < NHALF; ++k) {
        const unsigned int e = (unsigned int)k + 1u;
        float* pb = (e & 1u) ? myb1 : myb0;

        // ---- phase 1: row conv of S (row r1, outputs [ob,ob+8)) ----
        float acc[8];
        #pragma unroll
        for (int j = 0; j < 8; ++j) acc[j] = 0.f;
        {
            const int rb = r1 * STS + ob;        // window c = ob-16 .. ob+23
            #pragma unroll
            for (int i = 0; i < 40; ++i) {
                float v = lds[rb + i];
                #pragma unroll
                for (int j = 0; j < 8; ++j) {
                    const int d = i - 16 - j;
                    if (d >= -RW && d <= RW)
                        acc[j] = fmaf(v, gt.g[d < 0 ? -d : d], acc[j]);
                }
            }
        }
        {   // publish to ring slot + own D^T rows (slots 16..31)
            float4* q = (float4*)(pb + r1 * 128 + ob);
            q[0] = make_float4(acc[0], acc[1], acc[2], acc[3]);
            q[1] = make_float4(acc[4], acc[5], acc[6], acc[7]);
            #pragma unroll
            for (int j = 0; j < 8; ++j)
                lds[DT0 + (ob + j) * STD + 16 + r1] = acc[j];
        }
        __threadfence();                          // device-visible before flag
        __syncthreads();
        if (t == 0)
            __hip_atomic_store(&flags[blk * 16], e, __ATOMIC_RELEASE,
                               __HIP_MEMORY_SCOPE_AGENT);
        if (t == 1 && band > 0) {
            while (__hip_atomic_load(&flags[(blk - 1) * 16], __ATOMIC_ACQUIRE,
                                     __HIP_MEMORY_SCOPE_AGENT) < e)
                __builtin_amdgcn_s_sleep(4);
        }
        if (t == 2 && band < 7) {
            while (__hip_atomic_load(&flags[(blk + 1) * 16], __ATOMIC_ACQUIRE,
                                     __HIP_MEMORY_SCOPE_AGENT) < e)
                __builtin_amdgcn_s_sleep(4);
        }
        __syncthreads();
        __threadfence();                          // invalidate before halo reads

        if (band > 0) {                           // top halo -> slots 0..15
            const float* src = bufs + ((blk - 1) * 2 + (int)(e & 1u)) * 2048;
            #pragma unroll
            for (int m = 0; m < 8; ++m) {
                int idx = t + NTH * m;
                lds[DT0 + (idx & 127) * STD + (idx >> 7)] = src[idx];
            }
        }
        if (band < 7) {                           // bottom halo -> slots 32..47
            const float* src = bufs + ((blk + 1) * 2 + (int)(e & 1u)) * 2048;
            #pragma unroll
            for (int m = 0; m < 8; ++m) {
                int idx = t + NTH * m;
                lds[DT0 + (idx & 127) * STD + 32 + (idx >> 7)] = src[idx];
            }
        }
        __syncthreads();

        // ---- phase 2: col conv over D^T (col c2, out rows [8rob,8rob+8)) ----
        float acc2[8];
        #pragma unroll
        for (int j = 0; j < 8; ++j) acc2[j] = 0.f;
        {
            const int rb = DT0 + c2 * STD + rob * 8;   // slots 8rob..8rob+39
            #pragma unroll
            for (int i = 0; i < 40; ++i) {
                float v = lds[rb + i];
                #pragma unroll
                for (int j = 0; j < 8; ++j) {
                    const int d = i - 16 - j;
                    if (d >= -RW && d <= RW)
                        acc2[j] = fmaf(v, gt.g[d < 0 ? -d : d], acc2[j]);
                }
            }
        }
        if (k == 19) {                            // final phi1: dot only
            #pragma unroll
            for (int j = 0; j < 8; ++j) {
                float Un = fmaxf(Ap1[j], 1e-20f) * __builtin_amdgcn_rcpf(acc2[j]);
                D1 = fmaf(Ap1[j], __logf(Un), D1);
            }
        } else if ((k & 1) == 0) {                // produce phi0 (uses a0)
            #pragma unroll
            for (int j = 0; j < 8; ++j) {
                float Un = fmaxf(Ap0[j], 1e-20f) * __builtin_amdgcn_rcpf(acc2[j]);
                if (k == 18) D0 = fmaf(Ap0[j], __logf(Un), D0);
                lds[(rob * 8 + j) * STS + SDAT + c2] = Un;
            }
        } else {                                  // produce phi1 (uses a1)
            #pragma unroll
            for (int j = 0; j < 8; ++j) {
                float Un = fmaxf(Ap1[j], 1e-20f) * __builtin_amdgcn_rcpf(acc2[j]);
                lds[(rob * 8 + j) * STS + SDAT + c2] = Un;
            }
        }
        __syncthreads();
    }

    // band partial of loss/eps: D0 + D1 - sum(max(a1,floor))
    float p = D0 + D1 - SA1C;
    #pragma unroll
    for (int off = 1; off < 64; off <<= 1)
        p += __shfl_xor(p, off, 64);
    if ((t & 63) == 0) lds[REDO + (t >> 6)] = p;
    __syncthreads();
    if (t == 0)
        part[blk] = lds[REDO] + lds[REDO + 1] + lds[REDO + 2] + lds[REDO + 3];
}

__global__ __launch_bounds__(64, 1)
void sw2_fin(const float* __restrict__ ws, float* __restrict__ out) {
    int p = threadIdx.x;
    if (p < 16) {
        const float* pt = ws + 2048 + p * 8;
        float s = 0.f;
        #pragma unroll
        for (int b = 0; b < 8; ++b) s += pt[b];   // fixed order: deterministic
        out[p] = 1e-3f * s;
    }
}

extern "C" void kernel_launch(void* const* d_in, const int* in_sizes, int n_in,
                              void* d_out, int out_size, void* d_ws, size_t ws_size,
                              hipStream_t stream) {
    const float* a0 = (const float*)d_in[0];   // (4,128,128) f32
    const float* a1 = (const float*)d_in[1];   // (4,128,128) f32
    float* out = (float*)d_out;                // (4,4) f32
    float* ws  = (float*)d_ws;                 // needs ~2.02 MB

    GTab gt;
    const float bb = 1e-3f / ((1.0f / 128.0f) * (1.0f / 128.0f));  // 16.384
    for (int d = 0; d <= RW; ++d)
        gt.g[d] = expf(-(float)(d * d) / bb);

    sw2_init<<<8, 256, 0, stream>>>((unsigned int*)d_ws);

    void* args[] = { (void*)&a0, (void*)&a1, (void*)&ws, (void*)&gt };
    hipLaunchCooperativeKernel((const void*)sw2_main, dim3(NBLK), dim3(NTH),
                               args, 0, stream);

    sw2_fin<<<1, 64, 0, stream>>>(ws, out);
}

// Round 8
// 155.730 us; speedup vs baseline: 4.1748x; 4.1748x over previous
//
#include <hip/hip_runtime.h>
#include <math.h>

// Sinkhorn W2, 16 pairs of 128x128, one block (one CU) per pair, fully fused.
// Linear-domain unnormalized iteration (validated rounds 3/4):
//   P' = max(a,1e-20) / (G * P * G),   phi = log P at the end.
// Each halfstep = TWO banded 128x128x128 matmuls on the MATRIX pipe
// (mfma_f32_32x32x16_bf16), both storing transposed; composed stored-domain
// recurrence is exactly Z'[j][i] = a[j][i] / (G Z G)[j][i]  (G symmetric).
// f32 accuracy via 3-term bf16 split: Phi*Ghi + Phi*Glo + Plo*Ghi (~2^-16).
// G = symmetric Toeplitz band (RW=16), register-resident; banded K: only
// chunks 2C-1..2C+2 of 8 contribute to col-block C (covers +-16 exactly).
#define RW 16
#define NH 20
#define NT 512
#define STU 140          // ushort row stride (280 B; 70 dwords -> 2-way banks = free)

typedef short short8 __attribute__((ext_vector_type(8)));
typedef short short4v __attribute__((ext_vector_type(4)));
typedef float f32x16 __attribute__((ext_vector_type(16)));

__device__ __forceinline__ unsigned short f2bf(float x) {
    unsigned u = __float_as_uint(x);
    return (unsigned short)((u + 0x7FFFu + ((u >> 16) & 1u)) >> 16);
}
__device__ __forceinline__ float bf2f(unsigned short h) {
    return __uint_as_float(((unsigned)h) << 16);
}

__global__ __launch_bounds__(NT, 2)
void sw2_mfma(const float* __restrict__ a0, const float* __restrict__ a1,
              float* __restrict__ out, float bb)
{
    extern __shared__ char ldsb[];
    unsigned short* Zh = (unsigned short*)ldsb;          // [128][STU] bf16 hi
    unsigned short* Zl = Zh + 128 * STU;                 // lo
    unsigned short* Uh = Zl + 128 * STU;                 // U^T hi
    unsigned short* Ul = Uh + 128 * STU;                 // U^T lo
    float* red   = (float*)(ldsb + (size_t)4 * 128 * STU * 2);
    float* stage = (float*)(ldsb + (size_t)2 * 128 * STU * 2); // overlays Uh/Ul (prologue only)

    const int t = threadIdx.x;
    const int pair = blockIdx.x;
    const float* __restrict__ A0 = a0 + (pair >> 2) * 16384;
    const float* __restrict__ A1 = a1 + (pair & 3) * 16384;

    const int l     = t & 63;
    const int w     = t >> 6;          // 8 waves
    const int C     = w & 3;           // output col-block (fixed per wave)
    const int R0    = (w >> 2) << 1;   // row-blocks R0, R0+1
    const int lrow  = l & 31;          // A-row / C-col within tile
    const int lhi   = l >> 5;          // k-half select
    const int jglob = 32 * C + lrow;   // global output column

    // ---- G fragments (B operand), register-resident: 4 chunks x {hi,lo} ----
    short8 Gh[4], Gl[4];
    const float rbb = -1.0f / bb;
    #pragma unroll
    for (int m = 0; m < 4; ++m) {
        const int kc = 2 * C - 1 + m;
        short8 gh; short8 gl;
        #pragma unroll
        for (int j = 0; j < 8; ++j) { gh[j] = 0; gl[j] = 0; }
        if (kc >= 0 && kc <= 7) {
            #pragma unroll
            for (int j = 0; j < 8; ++j) {
                int k = 16 * kc + 8 * lhi + j;
                int d = k - jglob; d = d < 0 ? -d : d;
                float g = (d <= RW) ? __expf(rbb * (float)(d * d)) : 0.0f;
                unsigned short h = f2bf(g);
                gh[j] = (short)h;
                gl[j] = (short)f2bf(g - bf2f(h));
            }
        }
        Gh[m] = gh; Gl[m] = gl;
    }

    // ---- prologue: transposed a-values at this thread's C-positions ----
    float aT0[2][16], aT1[2][16];
    float SA1C = 0.f;
    for (int rep = 0; rep < 32; ++rep) {               // stage a0 (padded 129)
        int idx = t + NT * rep;
        stage[(idx >> 7) * 129 + (idx & 127)] = A0[idx];
    }
    __syncthreads();
    #pragma unroll
    for (int tau = 0; tau < 2; ++tau) {
        #pragma unroll
        for (int q = 0; q < 16; ++q) {
            int rho = (q & 3) + 8 * (q >> 2) + 4 * lhi;
            int i = 32 * (R0 + tau) + rho;
            aT0[tau][q] = stage[jglob * 129 + i];      // a0[j][i]
        }
    }
    __syncthreads();
    for (int rep = 0; rep < 32; ++rep) {               // stage a1
        int idx = t + NT * rep;
        stage[(idx >> 7) * 129 + (idx & 127)] = A1[idx];
    }
    __syncthreads();
    #pragma unroll
    for (int tau = 0; tau < 2; ++tau) {
        #pragma unroll
        for (int q = 0; q < 16; ++q) {
            int rho = (q & 3) + 8 * (q >> 2) + 4 * lhi;
            int i = 32 * (R0 + tau) + rho;
            float v = stage[jglob * 129 + i];          // a1[j][i]
            aT1[tau][q] = v;
            SA1C += fmaxf(v, 1e-20f);                  // sum p == sum max(a1,floor)
        }
    }
    __syncthreads();

    // ---- init P = exp(phi1=0) = 1 ----
    for (int i = t; i < 128 * STU; i += NT) { Zh[i] = 0x3F80; Zl[i] = 0; }
    __syncthreads();

    float D0 = 0.f, D1 = 0.f;

    #pragma unroll 1
    for (int k = 0; k < NH; ++k) {
        // ======== M1: U = P*G, write U^T (bf16 hi/lo) ========
        #pragma unroll
        for (int tau = 0; tau < 2; ++tau) {
            const int arow = 32 * (R0 + tau) + lrow;
            f32x16 acc = {};
            #pragma unroll
            for (int m = 0; m < 4; ++m) {
                const int kc = 2 * C - 1 + m;
                if (kc >= 0 && kc <= 7) {
                    const int base = arow * STU + 16 * kc + 8 * lhi;
                    short4v h0 = *(const short4v*)(Zh + base);
                    short4v h1 = *(const short4v*)(Zh + base + 4);
                    short4v l0 = *(const short4v*)(Zl + base);
                    short4v l1 = *(const short4v*)(Zl + base + 4);
                    short8 ah = {h0[0],h0[1],h0[2],h0[3],h1[0],h1[1],h1[2],h1[3]};
                    short8 al = {l0[0],l0[1],l0[2],l0[3],l1[0],l1[1],l1[2],l1[3]};
                    acc = __builtin_amdgcn_mfma_f32_32x32x16_bf16(ah, Gh[m], acc, 0, 0, 0);
                    acc = __builtin_amdgcn_mfma_f32_32x32x16_bf16(ah, Gl[m], acc, 0, 0, 0);
                    acc = __builtin_amdgcn_mfma_f32_32x32x16_bf16(al, Gh[m], acc, 0, 0, 0);
                }
            }
            #pragma unroll
            for (int qg = 0; qg < 4; ++qg) {
                const int i0 = 32 * (R0 + tau) + 8 * qg + 4 * lhi;
                unsigned short h[4], lo[4];
                #pragma unroll
                for (int e = 0; e < 4; ++e) {
                    float v = acc[4 * qg + e];
                    h[e]  = f2bf(v);
                    lo[e] = f2bf(v - bf2f(h[e]));
                }
                uint2 ph, pl;
                ph.x = (unsigned)h[0]  | ((unsigned)h[1]  << 16);
                ph.y = (unsigned)h[2]  | ((unsigned)h[3]  << 16);
                pl.x = (unsigned)lo[0] | ((unsigned)lo[1] << 16);
                pl.y = (unsigned)lo[2] | ((unsigned)lo[3] << 16);
                *(uint2*)(Uh + jglob * STU + i0) = ph;
                *(uint2*)(Ul + jglob * STU + i0) = pl;
            }
        }
        __syncthreads();

        // ======== M2: V = U^T*G = (G P G)^T, divide, write P' transposed ======
        #pragma unroll
        for (int tau = 0; tau < 2; ++tau) {
            const int arow = 32 * (R0 + tau) + lrow;
            f32x16 acc = {};
            #pragma unroll
            for (int m = 0; m < 4; ++m) {
                const int kc = 2 * C - 1 + m;
                if (kc >= 0 && kc <= 7) {
                    const int base = arow * STU + 16 * kc + 8 * lhi;
                    short4v h0 = *(const short4v*)(Uh + base);
                    short4v h1 = *(const short4v*)(Uh + base + 4);
                    short4v l0 = *(const short4v*)(Ul + base);
                    short4v l1 = *(const short4v*)(Ul + base + 4);
                    short8 ah = {h0[0],h0[1],h0[2],h0[3],h1[0],h1[1],h1[2],h1[3]};
                    short8 al = {l0[0],l0[1],l0[2],l0[3],l1[0],l1[1],l1[2],l1[3]};
                    acc = __builtin_amdgcn_mfma_f32_32x32x16_bf16(ah, Gh[m], acc, 0, 0, 0);
                    acc = __builtin_amdgcn_mfma_f32_32x32x16_bf16(ah, Gl[m], acc, 0, 0, 0);
                    acc = __builtin_amdgcn_mfma_f32_32x32x16_bf16(al, Gh[m], acc, 0, 0, 0);
                }
            }
            #pragma unroll
            for (int qg = 0; qg < 4; ++qg) {
                const int i0 = 32 * (R0 + tau) + 8 * qg + 4 * lhi;
                unsigned short h[4], lo[4];
                #pragma unroll
                for (int e = 0; e < 4; ++e) {
                    const int q = 4 * qg + e;
                    float av = (k & 1) ? aT1[tau][q] : aT0[tau][q];
                    float Un = fmaxf(av, 1e-20f) * __builtin_amdgcn_rcpf(acc[q]);
                    if (k == 18) D0 += av * __logf(Un);        // final phi0 dot
                    else if (k == 19) D1 += av * __logf(Un);   // final phi1 dot
                    h[e]  = f2bf(Un);
                    lo[e] = f2bf(Un - bf2f(h[e]));
                }
                if (k < NH - 1) {
                    uint2 ph, pl;
                    ph.x = (unsigned)h[0]  | ((unsigned)h[1]  << 16);
                    ph.y = (unsigned)h[2]  | ((unsigned)h[3]  << 16);
                    pl.x = (unsigned)lo[0] | ((unsigned)lo[1] << 16);
                    pl.y = (unsigned)lo[2] | ((unsigned)lo[3] << 16);
                    *(uint2*)(Zh + jglob * STU + i0) = ph;
                    *(uint2*)(Zl + jglob * STU + i0) = pl;
                }
            }
        }
        __syncthreads();
    }

    // ---- loss/eps = D0 + D1 - sum(max(a1,floor)) ; block reduce ----
    float part = D0 + D1 - SA1C;
    #pragma unroll
    for (int off = 1; off < 64; off <<= 1)
        part += __shfl_xor(part, off, 64);
    if (l == 0) red[w] = part;
    __syncthreads();
    if (t == 0) {
        float s = 0.f;
        #pragma unroll
        for (int i = 0; i < 8; ++i) s += red[i];
        out[pair] = 1e-3f * s;
    }
}

extern "C" void kernel_launch(void* const* d_in, const int* in_sizes, int n_in,
                              void* d_out, int out_size, void* d_ws, size_t ws_size,
                              hipStream_t stream) {
    const float* a0 = (const float*)d_in[0];   // (4,128,128) f32
    const float* a1 = (const float*)d_in[1];   // (4,128,128) f32
    float* out = (float*)d_out;                // (4,4) f32

    const float bb = 1e-3f / ((1.0f / 128.0f) * (1.0f / 128.0f));  // 16.384

    const size_t ldsBytes = (size_t)4 * 128 * STU * 2 + 64;        // 143,424 B
    (void)hipFuncSetAttribute(reinterpret_cast<const void*>(sw2_mfma),
                              hipFuncAttributeMaxDynamicSharedMemorySize,
                              (int)ldsBytes);

    hipLaunchKernelGGL(sw2_mfma, dim3(16), dim3(NT), ldsBytes, stream,
                       a0, a1, out, bb);
}

// Round 10
// 124.982 us; speedup vs baseline: 5.2019x; 1.2460x over previous
//
#include <hip/hip_runtime.h>
#include <math.h>

// Sinkhorn W2, 16 pairs of 128x128, one block (one CU) per pair, fully fused.
// Linear-domain unnormalized iteration:  P' = max(a,1e-20) / (G P G),
// phi = log P recovered only in the final two halfsteps' dot products.
// Each halfstep = TWO banded 128x128x128 matmuls on the matrix pipe
// (mfma_f32_32x32x16_bf16), both storing transposed; stored-domain
// recurrence is exactly Z'[j][i] = a[j][i] / (G Z G)[j][i]  (G symmetric).
// f32 accuracy via 3-term bf16 TRUNCATION split (hi = top 16 bits, lo =
// exact residual truncated): Zhi*Ghi + Zhi*Glo + Zlo*Ghi  (~2^-16 operand).
// 16 waves: one 32x32 output tile per wave per matmul (R=w>>2, C=w&3).
// Banded K: only chunks 2C-1..2C+2 of 8 contribute to col-block C (+-16).
#define RW 16
#define NH 20
#define NT 1024
#define STU 140          // ushort row stride (280 B); measured conflict-free

typedef short short8 __attribute__((ext_vector_type(8)));
typedef short short4v __attribute__((ext_vector_type(4)));
typedef float f32x16 __attribute__((ext_vector_type(16)));

__device__ __forceinline__ unsigned short f2bf(float x) {   // RNE (G setup only)
    unsigned u = __float_as_uint(x);
    return (unsigned short)((u + 0x7FFFu + ((u >> 16) & 1u)) >> 16);
}
__device__ __forceinline__ float bf2f(unsigned short h) {
    return __uint_as_float(((unsigned)h) << 16);
}

// Truncation hi/lo split of 4 f32 -> packed bf16x2 words (cheap: no RNE).
__device__ __forceinline__ void split4(float v0, float v1, float v2, float v3,
                                       uint2& ph, uint2& pl) {
    unsigned u0 = __float_as_uint(v0), u1 = __float_as_uint(v1);
    unsigned u2 = __float_as_uint(v2), u3 = __float_as_uint(v3);
    ph.x = (u0 >> 16) | (u1 & 0xFFFF0000u);
    ph.y = (u2 >> 16) | (u3 & 0xFFFF0000u);
    float l0 = v0 - __uint_as_float(u0 & 0xFFFF0000u);
    float l1 = v1 - __uint_as_float(u1 & 0xFFFF0000u);
    float l2 = v2 - __uint_as_float(u2 & 0xFFFF0000u);
    float l3 = v3 - __uint_as_float(u3 & 0xFFFF0000u);
    pl.x = (__float_as_uint(l0) >> 16) | (__float_as_uint(l1) & 0xFFFF0000u);
    pl.y = (__float_as_uint(l2) >> 16) | (__float_as_uint(l3) & 0xFFFF0000u);
}

__global__ __launch_bounds__(NT, 1)
void sw2_mfma(const float* __restrict__ a0, const float* __restrict__ a1,
              float* __restrict__ out, float bb)
{
    extern __shared__ char ldsb[];
    unsigned short* Zh = (unsigned short*)ldsb;          // [128][STU] bf16 hi
    unsigned short* Zl = Zh + 128 * STU;                 // lo
    unsigned short* Uh = Zl + 128 * STU;                 // U^T hi
    unsigned short* Ul = Uh + 128 * STU;                 // U^T lo
    float* red   = (float*)(ldsb + (size_t)4 * 128 * STU * 2);
    float* stage = (float*)(ldsb + (size_t)2 * 128 * STU * 2); // overlays Uh/Ul (prologue only)

    const int t = threadIdx.x;
    const int pair = blockIdx.x;
    const float* __restrict__ A0 = a0 + (pair >> 2) * 16384;
    const float* __restrict__ A1 = a1 + (pair & 3) * 16384;

    const int l     = t & 63;
    const int w     = t >> 6;          // 16 waves
    const int C     = w & 3;           // output col-block
    const int R     = w >> 2;          // output row-block (one tile per wave)
    const int lrow  = l & 31;
    const int lhi   = l >> 5;
    const int jglob = 32 * C + lrow;   // global output column

    // ---- G fragments (B operand), register-resident: 4 chunks x {hi,lo} ----
    short8 Gh[4], Gl[4];
    const float rbb = -1.0f / bb;
    #pragma unroll
    for (int m = 0; m < 4; ++m) {
        const int kc = 2 * C - 1 + m;
        short8 gh; short8 gl;
        #pragma unroll
        for (int j = 0; j < 8; ++j) { gh[j] = 0; gl[j] = 0; }
        if (kc >= 0 && kc <= 7) {
            #pragma unroll
            for (int j = 0; j < 8; ++j) {
                int k = 16 * kc + 8 * lhi + j;
                int d = k - jglob; d = d < 0 ? -d : d;
                float g = (d <= RW) ? __expf(rbb * (float)(d * d)) : 0.0f;
                unsigned short h = f2bf(g);
                gh[j] = (short)h;
                gl[j] = (short)f2bf(g - bf2f(h));
            }
        }
        Gh[m] = gh; Gl[m] = gl;
    }

    // ---- prologue: transposed a-values at this thread's C-positions ----
    float aT0[16], aT1[16];
    float SA1C = 0.f;
    for (int rep = 0; rep < 16; ++rep) {               // stage a0 (padded 129)
        int idx = t + NT * rep;
        stage[(idx >> 7) * 129 + (idx & 127)] = A0[idx];
    }
    __syncthreads();
    #pragma unroll
    for (int q = 0; q < 16; ++q) {
        int rho = (q & 3) + 8 * (q >> 2) + 4 * lhi;
        aT0[q] = stage[jglob * 129 + 32 * R + rho];    // a0[j][i]
    }
    __syncthreads();
    for (int rep = 0; rep < 16; ++rep) {               // stage a1
        int idx = t + NT * rep;
        stage[(idx >> 7) * 129 + (idx & 127)] = A1[idx];
    }
    __syncthreads();
    #pragma unroll
    for (int q = 0; q < 16; ++q) {
        int rho = (q & 3) + 8 * (q >> 2) + 4 * lhi;
        float v = stage[jglob * 129 + 32 * R + rho];   // a1[j][i]
        aT1[q] = v;
        SA1C += fmaxf(v, 1e-20f);                      // sum p == sum max(a1,floor)
    }
    __syncthreads();

    // ---- init P = exp(phi1=0) = 1 ----
    for (int i = t; i < 128 * STU; i += NT) { Zh[i] = 0x3F80; Zl[i] = 0; }
    __syncthreads();

    float D0 = 0.f, D1 = 0.f;
    const int arow = 32 * R + lrow;

    #pragma unroll 1
    for (int k = 0; k < NH; ++k) {
        // ======== M1: U = P*G, write U^T (bf16 hi/lo) ========
        {
            f32x16 acc = {};
            #pragma unroll
            for (int m = 0; m < 4; ++m) {
                const int kc = 2 * C - 1 + m;
                if (kc >= 0 && kc <= 7) {
                    const int base = arow * STU + 16 * kc + 8 * lhi;
                    short4v h0 = *(const short4v*)(Zh + base);
                    short4v h1 = *(const short4v*)(Zh + base + 4);
                    short4v l0 = *(const short4v*)(Zl + base);
                    short4v l1 = *(const short4v*)(Zl + base + 4);
                    short8 ah = {h0[0],h0[1],h0[2],h0[3],h1[0],h1[1],h1[2],h1[3]};
                    short8 al = {l0[0],l0[1],l0[2],l0[3],l1[0],l1[1],l1[2],l1[3]};
                    acc = __builtin_amdgcn_mfma_f32_32x32x16_bf16(ah, Gh[m], acc, 0, 0, 0);
                    acc = __builtin_amdgcn_mfma_f32_32x32x16_bf16(ah, Gl[m], acc, 0, 0, 0);
                    acc = __builtin_amdgcn_mfma_f32_32x32x16_bf16(al, Gh[m], acc, 0, 0, 0);
                }
            }
            #pragma unroll
            for (int qg = 0; qg < 4; ++qg) {
                const int i0 = 32 * R + 8 * qg + 4 * lhi;
                uint2 ph, pl;
                split4(acc[4*qg], acc[4*qg+1], acc[4*qg+2], acc[4*qg+3], ph, pl);
                *(uint2*)(Uh + jglob * STU + i0) = ph;
                *(uint2*)(Ul + jglob * STU + i0) = pl;
            }
        }
        __syncthreads();

        // ======== M2: V = U^T*G = (G P G)^T, divide, write P' transposed ======
        {
            f32x16 acc = {};
            #pragma unroll
            for (int m = 0; m < 4; ++m) {
                const int kc = 2 * C - 1 + m;
                if (kc >= 0 && kc <= 7) {
                    const int base = arow * STU + 16 * kc + 8 * lhi;
                    short4v h0 = *(const short4v*)(Uh + base);
                    short4v h1 = *(const short4v*)(Uh + base + 4);
                    short4v l0 = *(const short4v*)(Ul + base);
                    short4v l1 = *(const short4v*)(Ul + base + 4);
                    short8 ah = {h0[0],h0[1],h0[2],h0[3],h1[0],h1[1],h1[2],h1[3]};
                    short8 al = {l0[0],l0[1],l0[2],l0[3],l1[0],l1[1],l1[2],l1[3]};
                    acc = __builtin_amdgcn_mfma_f32_32x32x16_bf16(ah, Gh[m], acc, 0, 0, 0);
                    acc = __builtin_amdgcn_mfma_f32_32x32x16_bf16(ah, Gl[m], acc, 0, 0, 0);
                    acc = __builtin_amdgcn_mfma_f32_32x32x16_bf16(al, Gh[m], acc, 0, 0, 0);
                }
            }
            #pragma unroll
            for (int qg = 0; qg < 4; ++qg) {
                const int i0 = 32 * R + 8 * qg + 4 * lhi;
                float un[4];
                #pragma unroll
                for (int e = 0; e < 4; ++e) {
                    const int q = 4 * qg + e;
                    float av = (k & 1) ? aT1[q] : aT0[q];
                    float Un = fmaxf(av, 1e-20f) * __builtin_amdgcn_rcpf(acc[q]);
                    if (k == 18) D0 += av * __logf(Un);        // final phi0 dot
                    else if (k == 19) D1 += av * __logf(Un);   // final phi1 dot
                    un[e] = Un;
                }
                if (k < NH - 1) {
                    uint2 ph, pl;
                    split4(un[0], un[1], un[2], un[3], ph, pl);
                    *(uint2*)(Zh + jglob * STU + i0) = ph;
                    *(uint2*)(Zl + jglob * STU + i0) = pl;
                }
            }
        }
        __syncthreads();
    }

    // ---- loss/eps = D0 + D1 - sum(max(a1,floor)) ; block reduce ----
    float part = D0 + D1 - SA1C;
    #pragma unroll
    for (int off = 1; off < 64; off <<= 1)
        part += __shfl_xor(part, off, 64);
    if (l == 0) red[w] = part;
    __syncthreads();
    if (t == 0) {
        float s = 0.f;
        #pragma unroll
        for (int i = 0; i < 16; ++i) s += red[i];
        out[pair] = 1e-3f * s;
    }
}

extern "C" void kernel_launch(void* const* d_in, const int* in_sizes, int n_in,
                              void* d_out, int out_size, void* d_ws, size_t ws_size,
                              hipStream_t stream) {
    const float* a0 = (const float*)d_in[0];   // (4,128,128) f32
    const float* a1 = (const float*)d_in[1];   // (4,128,128) f32
    float* out = (float*)d_out;                // (4,4) f32

    const float bb = 1e-3f / ((1.0f / 128.0f) * (1.0f / 128.0f));  // 16.384

    const size_t ldsBytes = (size_t)4 * 128 * STU * 2 + 64;        // 143,424 B
    (void)hipFuncSetAttribute(reinterpret_cast<const void*>(sw2_mfma),
                              hipFuncAttributeMaxDynamicSharedMemorySize,
                              (int)ldsBytes);

    hipLaunchKernelGGL(sw2_mfma, dim3(16), dim3(NT), ldsBytes, stream,
                       a0, a1, out, bb);
}

// Round 11
// 111.869 us; speedup vs baseline: 5.8116x; 1.1172x over previous
//
#include <hip/hip_runtime.h>
#include <hip/hip_bf16.h>
#include <math.h>

// Sinkhorn W2, 16 pairs of 128x128, one block (one CU) per pair, fully fused.
// Linear-domain unnormalized iteration:  P' = max(a,1e-20) / (G P G).
// Each halfstep = TWO banded 128^3 matmuls (mfma_f32_32x32x16_bf16), both
// storing transposed; stored-domain recurrence Z'[j][i] = a[j][i]/(G Z G)[j][i].
// TWO-TIER PRECISION:
//   k <= 15: Z,U stored bf16-RNE hi-only (2 MFMA/chunk: ah*Gh + ah*Gl).
//            Elementwise RNE noise (2^-9, zero-mean) is annihilated by the
//            blur itself (x0.31/axis) -> ~1e-4 relative, invisible in loss.
//   k >= 16: full 3-term truncation split (hi + exact-residual lo, ~2^-16)
//            so the k=18/19 log-dots are unperturbed.
// G always 2-term (Gh+Gl): its rounding is a systematic operator error that
// accumulates across halfsteps, so it must stay at 2^-17.
#define RW 16
#define NH 20
#define NT 1024
#define STU 140          // ushort row stride (280 B); measured conflict-free

typedef short short8 __attribute__((ext_vector_type(8)));
typedef short short4v __attribute__((ext_vector_type(4)));
typedef float f32x16 __attribute__((ext_vector_type(16)));

__device__ __forceinline__ unsigned short f2bf(float x) {   // RNE (G setup only)
    unsigned u = __float_as_uint(x);
    return (unsigned short)((u + 0x7FFFu + ((u >> 16) & 1u)) >> 16);
}
__device__ __forceinline__ float bf2f(unsigned short h) {
    return __uint_as_float(((unsigned)h) << 16);
}

// RNE pack of two f32 -> bf16x2 word (compiler emits v_cvt_pk_bf16_f32).
__device__ __forceinline__ unsigned packRNE(float a, float b) {
    __hip_bfloat162 h2 = __float22bfloat162_rn(make_float2(a, b));
    union { __hip_bfloat162 h; unsigned u; } cv; cv.h = h2; return cv.u;
}

// Truncation hi/lo split of 4 f32 -> packed bf16x2 words (lo = exact residual).
__device__ __forceinline__ void split4(float v0, float v1, float v2, float v3,
                                       uint2& ph, uint2& pl) {
    unsigned u0 = __float_as_uint(v0), u1 = __float_as_uint(v1);
    unsigned u2 = __float_as_uint(v2), u3 = __float_as_uint(v3);
    ph.x = (u0 >> 16) | (u1 & 0xFFFF0000u);
    ph.y = (u2 >> 16) | (u3 & 0xFFFF0000u);
    float l0 = v0 - __uint_as_float(u0 & 0xFFFF0000u);
    float l1 = v1 - __uint_as_float(u1 & 0xFFFF0000u);
    float l2 = v2 - __uint_as_float(u2 & 0xFFFF0000u);
    float l3 = v3 - __uint_as_float(u3 & 0xFFFF0000u);
    pl.x = (__float_as_uint(l0) >> 16) | (__float_as_uint(l1) & 0xFFFF0000u);
    pl.y = (__float_as_uint(l2) >> 16) | (__float_as_uint(l3) & 0xFFFF0000u);
}

__device__ __forceinline__ short8 ld8(const unsigned short* p) {
    short4v a = *(const short4v*)(p);
    short4v b = *(const short4v*)(p + 4);
    return short8{a[0],a[1],a[2],a[3],b[0],b[1],b[2],b[3]};
}

template <bool USELO>
__device__ __forceinline__ f32x16 bandmm(const unsigned short* __restrict__ Sh,
                                         const unsigned short* __restrict__ Sl,
                                         int arow, int C, int lhi,
                                         const short8 (&Gh)[4], const short8 (&Gl)[4]) {
    f32x16 acc = {};
    #pragma unroll
    for (int m = 0; m < 4; ++m) {
        const int kc = 2 * C - 1 + m;
        if (kc >= 0 && kc <= 7) {
            const int base = arow * STU + 16 * kc + 8 * lhi;
            short8 ah = ld8(Sh + base);
            acc = __builtin_amdgcn_mfma_f32_32x32x16_bf16(ah, Gh[m], acc, 0, 0, 0);
            acc = __builtin_amdgcn_mfma_f32_32x32x16_bf16(ah, Gl[m], acc, 0, 0, 0);
            if (USELO) {
                short8 al = ld8(Sl + base);
                acc = __builtin_amdgcn_mfma_f32_32x32x16_bf16(al, Gh[m], acc, 0, 0, 0);
            }
        }
    }
    return acc;
}

__global__ __launch_bounds__(NT, 4)
void sw2_mfma(const float* __restrict__ a0, const float* __restrict__ a1,
              float* __restrict__ out, float bb)
{
    extern __shared__ char ldsb[];
    unsigned short* Zh = (unsigned short*)ldsb;          // [128][STU] bf16 hi
    unsigned short* Zl = Zh + 128 * STU;                 // lo (full steps only)
    unsigned short* Uh = Zl + 128 * STU;                 // U^T hi
    unsigned short* Ul = Uh + 128 * STU;                 // U^T lo (full steps)
    float* red   = (float*)(ldsb + (size_t)4 * 128 * STU * 2);
    float* stage = (float*)(ldsb + (size_t)2 * 128 * STU * 2); // overlays Uh/Ul (prologue only)

    const int t = threadIdx.x;
    const int pair = blockIdx.x;
    const float* __restrict__ A0 = a0 + (pair >> 2) * 16384;
    const float* __restrict__ A1 = a1 + (pair & 3) * 16384;

    const int l     = t & 63;
    const int w     = t >> 6;          // 16 waves
    const int C     = w & 3;           // output col-block
    const int R     = w >> 2;          // output row-block
    const int lrow  = l & 31;
    const int lhi   = l >> 5;
    const int jglob = 32 * C + lrow;   // global output column
    const int R32   = 32 * R;
    const int arow  = R32 + lrow;
    const int wb    = jglob * STU;

    // ---- G fragments (B operand), register-resident: 4 chunks x {hi,lo} ----
    short8 Gh[4], Gl[4];
    const float rbb = -1.0f / bb;
    #pragma unroll
    for (int m = 0; m < 4; ++m) {
        const int kc = 2 * C - 1 + m;
        short8 gh; short8 gl;
        #pragma unroll
        for (int j = 0; j < 8; ++j) { gh[j] = 0; gl[j] = 0; }
        if (kc >= 0 && kc <= 7) {
            #pragma unroll
            for (int j = 0; j < 8; ++j) {
                int k = 16 * kc + 8 * lhi + j;
                int d = k - jglob; d = d < 0 ? -d : d;
                float g = (d <= RW) ? __expf(rbb * (float)(d * d)) : 0.0f;
                unsigned short h = f2bf(g);
                gh[j] = (short)h;
                gl[j] = (short)f2bf(g - bf2f(h));
            }
        }
        Gh[m] = gh; Gl[m] = gl;
    }

    // ---- prologue: CLAMPED transposed a-values at this thread's C-positions ----
    float aT0c[16], aT1c[16];
    float SA1C = 0.f;
    for (int rep = 0; rep < 16; ++rep) {               // stage a0 (padded 129)
        int idx = t + NT * rep;
        stage[(idx >> 7) * 129 + (idx & 127)] = A0[idx];
    }
    __syncthreads();
    #pragma unroll
    for (int q = 0; q < 16; ++q) {
        int rho = (q & 3) + 8 * (q >> 2) + 4 * lhi;
        aT0c[q] = fmaxf(stage[jglob * 129 + R32 + rho], 1e-20f);
    }
    __syncthreads();
    for (int rep = 0; rep < 16; ++rep) {               // stage a1
        int idx = t + NT * rep;
        stage[(idx >> 7) * 129 + (idx & 127)] = A1[idx];
    }
    __syncthreads();
    #pragma unroll
    for (int q = 0; q < 16; ++q) {
        int rho = (q & 3) + 8 * (q >> 2) + 4 * lhi;
        float v = fmaxf(stage[jglob * 129 + R32 + rho], 1e-20f);
        aT1c[q] = v;
        SA1C += v;                                     // sum p == sum max(a1,floor)
    }
    __syncthreads();

    // ---- init P = exp(phi1=0) = 1 (hi exact; lo irrelevant until k=17) ----
    for (int i = t; i < 128 * STU; i += NT) { Zh[i] = 0x3F80; Zl[i] = 0; }
    __syncthreads();

    float D0 = 0.f, D1 = 0.f;

    #pragma unroll 1
    for (int k = 0; k < NH; ++k) {
        // ======== M1: U = Z*G, write U^T ========
        {
            f32x16 acc = (k >= 17) ? bandmm<true >(Zh, Zl, arow, C, lhi, Gh, Gl)
                                   : bandmm<false>(Zh, Zl, arow, C, lhi, Gh, Gl);
            if (k >= 16) {                 // full split store
                #pragma unroll
                for (int qg = 0; qg < 4; ++qg) {
                    const int i0 = R32 + 8 * qg + 4 * lhi;
                    uint2 ph, pl;
                    split4(acc[4*qg], acc[4*qg+1], acc[4*qg+2], acc[4*qg+3], ph, pl);
                    *(uint2*)(Uh + wb + i0) = ph;
                    *(uint2*)(Ul + wb + i0) = pl;
                }
            } else {                       // cheap RNE hi-only store
                #pragma unroll
                for (int qg = 0; qg < 4; ++qg) {
                    const int i0 = R32 + 8 * qg + 4 * lhi;
                    uint2 ph;
                    ph.x = packRNE(acc[4*qg],   acc[4*qg+1]);
                    ph.y = packRNE(acc[4*qg+2], acc[4*qg+3]);
                    *(uint2*)(Uh + wb + i0) = ph;
                }
            }
        }
        __syncthreads();

        // ======== M2: V = U^T*G, divide, write Z' transposed ========
        {
            f32x16 acc = (k >= 16) ? bandmm<true >(Uh, Ul, arow, C, lhi, Gh, Gl)
                                   : bandmm<false>(Uh, Ul, arow, C, lhi, Gh, Gl);
            if (k < 16) {                  // cheap: RNE hi-only
                if (k & 1) {
                    #pragma unroll
                    for (int qg = 0; qg < 4; ++qg) {
                        const int i0 = R32 + 8 * qg + 4 * lhi;
                        float u0 = aT1c[4*qg]   * __builtin_amdgcn_rcpf(acc[4*qg]);
                        float u1 = aT1c[4*qg+1] * __builtin_amdgcn_rcpf(acc[4*qg+1]);
                        float u2 = aT1c[4*qg+2] * __builtin_amdgcn_rcpf(acc[4*qg+2]);
                        float u3 = aT1c[4*qg+3] * __builtin_amdgcn_rcpf(acc[4*qg+3]);
                        uint2 ph; ph.x = packRNE(u0, u1); ph.y = packRNE(u2, u3);
                        *(uint2*)(Zh + wb + i0) = ph;
                    }
                } else {
                    #pragma unroll
                    for (int qg = 0; qg < 4; ++qg) {
                        const int i0 = R32 + 8 * qg + 4 * lhi;
                        float u0 = aT0c[4*qg]   * __builtin_amdgcn_rcpf(acc[4*qg]);
                        float u1 = aT0c[4*qg+1] * __builtin_amdgcn_rcpf(acc[4*qg+1]);
                        float u2 = aT0c[4*qg+2] * __builtin_amdgcn_rcpf(acc[4*qg+2]);
                        float u3 = aT0c[4*qg+3] * __builtin_amdgcn_rcpf(acc[4*qg+3]);
                        uint2 ph; ph.x = packRNE(u0, u1); ph.y = packRNE(u2, u3);
                        *(uint2*)(Zh + wb + i0) = ph;
                    }
                }
            } else if (k == 16) {          // full store, a0
                #pragma unroll
                for (int qg = 0; qg < 4; ++qg) {
                    const int i0 = R32 + 8 * qg + 4 * lhi;
                    float un[4];
                    #pragma unroll
                    for (int e = 0; e < 4; ++e)
                        un[e] = aT0c[4*qg+e] * __builtin_amdgcn_rcpf(acc[4*qg+e]);
                    uint2 ph, pl; split4(un[0], un[1], un[2], un[3], ph, pl);
                    *(uint2*)(Zh + wb + i0) = ph;
                    *(uint2*)(Zl + wb + i0) = pl;
                }
            } else if (k == 17) {          // full store, a1
                #pragma unroll
                for (int qg = 0; qg < 4; ++qg) {
                    const int i0 = R32 + 8 * qg + 4 * lhi;
                    float un[4];
                    #pragma unroll
                    for (int e = 0; e < 4; ++e)
                        un[e] = aT1c[4*qg+e] * __builtin_amdgcn_rcpf(acc[4*qg+e]);
                    uint2 ph, pl; split4(un[0], un[1], un[2], un[3], ph, pl);
                    *(uint2*)(Zh + wb + i0) = ph;
                    *(uint2*)(Zl + wb + i0) = pl;
                }
            } else if (k == 18) {          // full store + D0 dot, a0
                #pragma unroll
                for (int qg = 0; qg < 4; ++qg) {
                    const int i0 = R32 + 8 * qg + 4 * lhi;
                    float un[4];
                    #pragma unroll
                    for (int e = 0; e < 4; ++e) {
                        float av = aT0c[4*qg+e];
                        un[e] = av * __builtin_amdgcn_rcpf(acc[4*qg+e]);
                        D0 += av * __logf(un[e]);
                    }
                    uint2 ph, pl; split4(un[0], un[1], un[2], un[3], ph, pl);
                    *(uint2*)(Zh + wb + i0) = ph;
                    *(uint2*)(Zl + wb + i0) = pl;
                }
            } else {                       // k == 19: D1 dot only, no store
                #pragma unroll
                for (int q = 0; q < 16; ++q) {
                    float av = aT1c[q];
                    float Un = av * __builtin_amdgcn_rcpf(acc[q]);
                    D1 += av * __logf(Un);
                }
            }
        }
        __syncthreads();
    }

    // ---- loss/eps = D0 + D1 - sum(max(a1,floor)) ; block reduce ----
    float part = D0 + D1 - SA1C;
    #pragma unroll
    for (int off = 1; off < 64; off <<= 1)
        part += __shfl_xor(part, off, 64);
    if (l == 0) red[w] = part;
    __syncthreads();
    if (t == 0) {
        float s = 0.f;
        #pragma unroll
        for (int i = 0; i < 16; ++i) s += red[i];
        out[pair] = 1e-3f * s;
    }
}

extern "C" void kernel_launch(void* const* d_in, const int* in_sizes, int n_in,
                              void* d_out, int out_size, void* d_ws, size_t ws_size,
                              hipStream_t stream) {
    const float* a0 = (const float*)d_in[0];   // (4,128,128) f32
    const float* a1 = (const float*)d_in[1];   // (4,128,128) f32
    float* out = (float*)d_out;                // (4,4) f32

    const float bb = 1e-3f / ((1.0f / 128.0f) * (1.0f / 128.0f));  // 16.384

    const size_t ldsBytes = (size_t)4 * 128 * STU * 2 + 64;        // 143,424 B
    (void)hipFuncSetAttribute(reinterpret_cast<const void*>(sw2_mfma),
                              hipFuncAttributeMaxDynamicSharedMemorySize,
                              (int)ldsBytes);

    hipLaunchKernelGGL(sw2_mfma, dim3(16), dim3(NT), ldsBytes, stream,
                       a0, a1, out, bb);
}